// Round 1
// baseline (122.092 us; speedup 1.0000x reference)
//
#include <hip/hip_runtime.h>
#include <hip/hip_bf16.h>

typedef __attribute__((ext_vector_type(4))) float f32x4;
typedef __attribute__((ext_vector_type(8))) short short8;

#define S_DIM 2048
#define D_DIM 64
#define KB 128
#define VSTR 136            // ushort stride per Vt row (128 + 8 pad)
#define NHEADS 32
#define QTILES (S_DIM / 64)

static __device__ __forceinline__ unsigned short f2bf(float x) {
    union { __hip_bfloat16 h; unsigned short u; } c;
    c.h = __float2bfloat16(x);
    return c.u;
}

__global__ __launch_bounds__(256)
void attn_mixer_kernel(const float* __restrict__ V,
                       const float* __restrict__ L,
                       float* __restrict__ O)
{
    __shared__ unsigned short vt[D_DIM * VSTR];   // 64 x 136 ushort = 17408 B

    const int tid  = threadIdx.x;
    const int wave = tid >> 6;
    const int lane = tid & 63;
    const int lr   = lane & 15;   // A-frag row / B-frag col / D col
    const int lg   = lane >> 4;   // k-group

    // XCD swizzle: all 32 Q-tiles of a head land on one XCD (V stays in its L2)
    const int bid  = blockIdx.x;
    const int xcd  = bid & 7;
    const int ixd  = bid >> 3;
    const int head = xcd * (NHEADS / 8) + (ixd >> 5);
    const int qt   = ixd & (QTILES - 1);

    const int i0 = qt * 64 + wave * 16;           // this wave's 16-row block
    const float* lrow  = L + ((size_t)head * S_DIM + (size_t)(i0 + lr)) * S_DIM;
    const float* vbase = V + (size_t)head * S_DIM * D_DIM;

    // staging role: thread stages Vt row d = sd, k-chunk sjc (32 j's)
    const int sd  = tid & 63;
    const int sjc = tid >> 6;

    float m_run = -INFINITY;
    float l_run = 0.0f;
    f32x4 acc[4] = {};            // 4 d-blocks of 16; lane: col=lr, rows=lg*4+r

    for (int jb = 0; jb < S_DIM; jb += KB) {
        __syncthreads();          // all reads of vt from prev step done
        // ---- stage V^T (bf16) into LDS: Vt[d][k], coalesced global reads ----
        {
            const float* vcol = vbase + (size_t)(jb + sjc * 32) * D_DIM + sd;
            #pragma unroll
            for (int h = 0; h < 4; ++h) {
                short8 w;
                #pragma unroll
                for (int e = 0; e < 8; ++e)
                    w[e] = (short)f2bf(vcol[(size_t)(h * 8 + e) * D_DIM]);
                *(short8*)(&vt[sd * VSTR + sjc * 32 + h * 8]) = w;
            }
        }
        __syncthreads();

        // ---- load P tile (16 rows x 128 k) straight into A-fragment layout ----
        float p[32];
        #pragma unroll
        for (int c = 0; c < 4; ++c) {
            const float* src = lrow + jb + c * 32 + lg * 8;
            f32x4 a = *(const f32x4*)(src);
            f32x4 b = *(const f32x4*)(src + 4);
            p[c*8+0]=a[0]; p[c*8+1]=a[1]; p[c*8+2]=a[2]; p[c*8+3]=a[3];
            p[c*8+4]=b[0]; p[c*8+5]=b[1]; p[c*8+6]=b[2]; p[c*8+7]=b[3];
        }

        // ---- online softmax (per 16-row group; 4 lane-groups share a row) ----
        float mt = p[0];
        #pragma unroll
        for (int i = 1; i < 32; ++i) mt = fmaxf(mt, p[i]);
        mt = fmaxf(mt, __shfl_xor(mt, 16));
        mt = fmaxf(mt, __shfl_xor(mt, 32));
        const float mnew  = fmaxf(m_run, mt);
        const float scale = __expf(m_run - mnew);   // first iter: exp(-inf)=0
        m_run = mnew;

        float ls = 0.0f;
        #pragma unroll
        for (int i = 0; i < 32; ++i) { p[i] = __expf(p[i] - mnew); ls += p[i]; }
        ls += __shfl_xor(ls, 16);
        ls += __shfl_xor(ls, 32);
        l_run = l_run * scale + ls;

        // rescale accumulators: row of acc reg r is lg*4+r; stat lives at lane==row
        #pragma unroll
        for (int r = 0; r < 4; ++r) {
            const float sr = __shfl(scale, lg * 4 + r);
            acc[0][r] *= sr; acc[1][r] *= sr; acc[2][r] *= sr; acc[3][r] *= sr;
        }

        // ---- P -> bf16 A-fragments ----
        short8 afr[4];
        #pragma unroll
        for (int c = 0; c < 4; ++c) {
            #pragma unroll
            for (int e = 0; e < 8; ++e)
                afr[c][e] = (short)f2bf(p[c*8+e]);
        }

        // ---- MFMA: acc[n] += P(16x32) x V(32x16) over 4 k-chunks ----
        #pragma unroll
        for (int c = 0; c < 4; ++c) {
            #pragma unroll
            for (int n = 0; n < 4; ++n) {
                short8 bfr = *(const short8*)&vt[(n * 16 + lr) * VSTR + c * 32 + lg * 8];
                acc[n] = __builtin_amdgcn_mfma_f32_16x16x32_bf16(afr[c], bfr, acc[n], 0, 0, 0);
            }
        }
    }

    // ---- epilogue: divide by row sums, store fp32 ----
    #pragma unroll
    for (int r = 0; r < 4; ++r) {
        const float li  = __shfl(l_run, lg * 4 + r);
        const float inv = 1.0f / li;
        float* orow = O + ((size_t)head * S_DIM + (size_t)(i0 + lg * 4 + r)) * D_DIM;
        #pragma unroll
        for (int n = 0; n < 4; ++n)
            orow[n * 16 + lr] = acc[n][r] * inv;
    }
}

extern "C" void kernel_launch(void* const* d_in, const int* in_sizes, int n_in,
                              void* d_out, int out_size, void* d_ws, size_t ws_size,
                              hipStream_t stream) {
    const float* v = (const float*)d_in[0];
    const float* l = (const float*)d_in[1];
    float* out     = (float*)d_out;
    dim3 grid(NHEADS * QTILES);   // 1024 blocks
    dim3 block(256);
    attn_mixer_kernel<<<grid, block, 0, stream>>>(v, l, out);
}